// Round 2
// baseline (282.398 us; speedup 1.0000x reference)
//
#include <hip/hip_runtime.h>
#include <math.h>

// Problem constants
#define D0 32
#define D1 256
#define D2 256
#define HS2 129            // rfft half-spectrum last dim
#define NVOX (D0*D1*D2)    // 2097152
#define KMAX 4
#define NK 9               // k in [-4,4]
#define NK2 5              // k2 in [0,4]
#define NCH 3
#define BATCH 4
#define FCH 3
#define NBC (BATCH*FCH)    // 12
// C layout: [ch][i0][i1][i2][2]  (i0=k0+4, i1=k1+4, i2=k2)
#define C_FLOATS (NCH*NK*NK*NK2*2)   // 2430
// S layout: [zy][32] floats; slot = ch*10 + k2*2 + reim  (30 used, pad to 32)
// -> all 30 per-row coefficients are wave-uniform contiguous: scalar loads.

typedef float v2f __attribute__((ext_vector_type(2)));

// 256 blocks x 256 threads: build dense C cube in LDS (scatter, ~fdim loads),
// then 32 zy rows/block, 81-mode sum split 8 ways across consecutive lanes,
// width-8 shuffle reduction.
__global__ __launch_bounds__(256) void build_S(
    const float* __restrict__ seeds, const float* __restrict__ Pk,
    const float* __restrict__ defscale, const int* __restrict__ feed_idx,
    int fdim, float* __restrict__ S)
{
    __shared__ float C[C_FLOATS];
    __shared__ int fed[NK*NK];
    int t = threadIdx.x;
    for (int i = t; i < C_FLOATS; i += 256) C[i] = 0.0f;
    if (t < NK*NK) fed[t] = 0;
    __syncthreads();
    float ds0 = defscale[0], ds1 = defscale[1], ds2 = defscale[2];
    const int STR_RI = D0 * D1 * HS2;   // 1056768
    const int STR_A  = D1 * HS2;        // 33024
    for (int j = t; j < fdim; j += 256) {
        int idx = feed_idx[j];
        int ri = idx / STR_RI; int r = idx - ri * STR_RI;
        int a  = r / STR_A;    r -= a * STR_A;
        int b  = r / HS2;      int c = r - b * HS2;
        int k0 = (a < D0/2) ? a : a - D0;
        int k1 = (b < D1/2) ? b : b - D1;
        if (k0 < -KMAX || k0 > KMAX || k1 < -KMAX || k1 > KMAX || c > KMAX) continue;
        int i0 = k0 + KMAX, i1 = k1 + KMAX;
        float pk = Pk[j];
        int base = ((i0*NK + i1)*NK2 + c)*2 + ri;
        C[base]                 = seeds[0*fdim + j] * pk * ds0;
        C[base + 1*NK*NK*NK2*2] = seeds[1*fdim + j] * pk * ds1;
        C[base + 2*NK*NK*NK2*2] = seeds[2*fdim + j] * pk * ds2;
        if (c == 0) fed[i0*NK + i1] = 1;
    }
    __syncthreads();
    // hermitian completion on the k2=0 plane: unfed <- conj(mirror)
    if (t < NK*NK && !fed[t]) {
        int i0 = t / NK, i1 = t - i0*NK;
        int m0 = (NK-1) - i0, m1 = (NK-1) - i1;
        for (int ch = 0; ch < NCH; ++ch) {
            int dst = ((ch*NK*NK + i0*NK + i1)*NK2 + 0)*2;
            int src = ((ch*NK*NK + m0*NK + m1)*NK2 + 0)*2;
            C[dst]   = C[src];
            C[dst+1] = -C[src+1];
        }
    }
    __syncthreads();

    int zyl = t >> 3;           // 0..31  (consecutive lanes share zyl)
    int g   = t & 7;            // mode group 0..7
    int zy = blockIdx.x * 32 + zyl;
    int z = zy >> 8, y = zy & 255;

    float w0r[NK], w0i[NK], w1r[NK], w1i[NK];
    {
        float th = (float)z * (6.28318530717958647692f / (float)D0);
        float sb, cb; __sincosf(th, &sb, &cb);
        w0r[KMAX] = 1.0f; w0i[KMAX] = 0.0f;
        float pr = 1.0f, pi = 0.0f;
        #pragma unroll
        for (int k = 1; k <= KMAX; ++k) {
            float nr = pr*cb - pi*sb, ni = pr*sb + pi*cb;
            pr = nr; pi = ni;
            w0r[KMAX+k] = pr; w0i[KMAX+k] = pi;
            w0r[KMAX-k] = pr; w0i[KMAX-k] = -pi;
        }
    }
    {
        float th = (float)y * (6.28318530717958647692f / (float)D1);
        float sb, cb; __sincosf(th, &sb, &cb);
        w1r[KMAX] = 1.0f; w1i[KMAX] = 0.0f;
        float pr = 1.0f, pi = 0.0f;
        #pragma unroll
        for (int k = 1; k <= KMAX; ++k) {
            float nr = pr*cb - pi*sb, ni = pr*sb + pi*cb;
            pr = nr; pi = ni;
            w1r[KMAX+k] = pr; w1i[KMAX+k] = pi;
            w1r[KMAX-k] = pr; w1i[KMAX-k] = -pi;
        }
    }

    float Sr[NCH*NK2], Si[NCH*NK2];
    #pragma unroll
    for (int i = 0; i < NCH*NK2; ++i) { Sr[i] = 0.0f; Si[i] = 0.0f; }

    for (int m = g; m < NK*NK; m += 8) {
        int i0 = m / NK, i1 = m - i0*NK;
        float Tr = w0r[i0]*w1r[i1] - w0i[i0]*w1i[i1];
        float Ti = w0r[i0]*w1i[i1] + w0i[i0]*w1r[i1];
        const float* Cp = C + m*NK2*2;
        #pragma unroll
        for (int ch = 0; ch < NCH; ++ch) {
            #pragma unroll
            for (int k2 = 0; k2 < NK2; ++k2) {
                float cr = Cp[ch*(NK*NK*NK2*2) + k2*2];
                float ci = Cp[ch*(NK*NK*NK2*2) + k2*2 + 1];
                int o = ch*NK2 + k2;
                Sr[o] += cr*Tr - ci*Ti;
                Si[o] += cr*Ti + ci*Tr;
            }
        }
    }

    #pragma unroll
    for (int off = 4; off >= 1; off >>= 1) {
        #pragma unroll
        for (int i = 0; i < NCH*NK2; ++i) {
            Sr[i] += __shfl_down(Sr[i], off, 8);
            Si[i] += __shfl_down(Si[i], off, 8);
        }
    }

    if (g == 0) {
        const float invN = 1.0f / (float)NVOX;
        float* Sp = S + (size_t)zy * 32;
        #pragma unroll
        for (int ch = 0; ch < NCH; ++ch) {
            #pragma unroll
            for (int k2 = 0; k2 < NK2; ++k2) {
                int o = ch*NK2 + k2;
                float sc = (k2 == 0) ? invN : 2.0f*invN;
                Sp[ch*10 + k2*2 + 0] = Sr[o] * sc;
                Sp[ch*10 + k2*2 + 1] = Si[o] * sc;
            }
        }
    }
}

// ROUND 2: 2x2 (z,y) quad per thread.
// Evidence so far: 24->12 gather instrs = neutral; forced 12-deep MLP
// (VGPR 20->28, single wait group) = neutral; VALUBusy 28%, HBM 17%,
// occupancy 81%. The invariant across all neutral edits is the per-lane
// dword-request count (24 dwords/sample: 4 rows x 2 x x 3 ch) and the
// cache-line footprint (~110 lines/wave -> ~900 MB of scattered L2/LLC
// line traffic at ~7 TB/s). 512 waves/CU x 1730 lane-requests / 307K cy
// = 2.9 req/cy ~= TA/TCP lane-request throughput. Both surviving
// bottleneck candidates scale with the SAME quantity, and the only way
// down is reuse across neighboring samples:
//   outputs (z,y),(z,y+1),(z+1,y),(z+1,y+1) share bilinear rows:
//   ~3z x 3y x 3ch = 27 row-loads per quad vs 4x12 = 48  => 1.78x fewer
//   requests AND lines (shared rows are L1-hot: same thread, back-to-back).
// x-trig is also shared across the quad. Loop kept unroll-1 so payload
// registers are reused -> VGPR stays <=~56, occupancy 8 blocks/CU.
// Predict: dur 128 -> ~75-95us, VALUBusy -> 35-45%, FETCH_SIZE ~same.
__global__ __launch_bounds__(256) void deform_sample(
    const float* __restrict__ fr, const float* __restrict__ S,
    float* __restrict__ out)
{
    int i = blockIdx.x;                 // 8192 blocks
    int u = i & 7;                      // XCD id = unit id
    int b  = u >> 1;                    // batch (channel group) 0..3
    int zh = u & 1;                     // z-half 0..1
    int j = i >> 3;                     // 0..1023 within unit; y-pair fastest
    int zb = (zh << 4) + ((j >> 7) << 1);   // even z base
    int yb = (j & 127) << 1;                // even y base
    int x = threadIdx.x;

    // cos/sin(k*theta) for k=1..4, theta = 2*pi*x/256  (shared by all 4 outputs)
    float th = (float)x * (6.28318530717958647692f / (float)D2);
    float sb, cb; __sincosf(th, &sb, &cb);
    float ckr[KMAX], cks[KMAX];
    ckr[0] = cb; cks[0] = sb;
    #pragma unroll
    for (int k = 1; k < KMAX; ++k) {
        float nr = ckr[k-1]*cb - cks[k-1]*sb;
        float ni = cks[k-1]*cb + ckr[k-1]*sb;
        ckr[k] = nr; cks[k] = ni;
    }

    const float* __restrict__ vbase = fr + ((size_t)(b*FCH) << 21);
    size_t obase = ((size_t)(b*FCH) << 21) + (size_t)x;

    #pragma unroll 1
    for (int q = 0; q < 4; ++q) {
        int z = zb + (q >> 1);
        int y = yb + (q & 1);
        int zy = (z << 8) + y;

        // 30 wave-uniform coefficients -> scalar loads (zy is wave-uniform)
        const float* __restrict__ Sp = S + (size_t)zy * 32;
        float s[30];
        #pragma unroll
        for (int qq = 0; qq < 30; ++qq) s[qq] = Sp[qq];

        float d[NCH];
        #pragma unroll
        for (int ch = 0; ch < NCH; ++ch) {
            float acc = s[ch*10 + 0];
            #pragma unroll
            for (int k = 1; k <= KMAX; ++k)
                acc += s[ch*10 + k*2]*ckr[k-1] - s[ch*10 + k*2 + 1]*cks[k-1];
            d[ch] = acc;
        }

        // coordinates collapse to: f = clip(coord - disp, 0, dim-1)
        float fz = fminf(fmaxf((float)z - d[0], 0.0f), (float)(D0-1));
        float fy = fminf(fmaxf((float)y - d[1], 0.0f), (float)(D1-1));
        float fx = fminf(fmaxf((float)x - d[2], 0.0f), (float)(D2-1));

        float z0f = floorf(fz), y0f = floorf(fy), x0f = floorf(fx);
        int z0 = (int)z0f, y0 = (int)y0f, x0 = (int)x0f;
        int z1 = min(z0 + 1, D0-1), y1 = min(y0 + 1, D1-1);
        float wz = fz - z0f, wy = fy - y0f, wx = fx - x0f;

        int xm = min(x0, D2-2);             // float2 stays in-row
        bool hi = (x0 > xm);                // x0 == 255 -> use (.y,.y)

        int o00 = (z0 << 16) + (y0 << 8) + xm;
        int o01 = (z0 << 16) + (y1 << 8) + xm;
        int o10 = (z1 << 16) + (y0 << 8) + xm;
        int o11 = (z1 << 16) + (y1 << 8) + xm;

        // issue all 12 float2 gathers before consuming
        v2f P[FCH][4];
        #pragma unroll
        for (int c = 0; c < FCH; ++c) {
            const float* __restrict__ v = vbase + ((size_t)c << 21);
            P[c][0] = *(const v2f*)(v + o00);
            P[c][1] = *(const v2f*)(v + o01);
            P[c][2] = *(const v2f*)(v + o10);
            P[c][3] = *(const v2f*)(v + o11);
        }

        size_t ob = obase + ((size_t)zy << 8);
        #pragma unroll
        for (int c = 0; c < FCH; ++c) {
            float a00 = hi ? P[c][0].y : P[c][0].x;
            float a01 = hi ? P[c][1].y : P[c][1].x;
            float a10 = hi ? P[c][2].y : P[c][2].x;
            float a11 = hi ? P[c][3].y : P[c][3].x;
            float c00 = a00 + wx * (P[c][0].y - a00);
            float c01 = a01 + wx * (P[c][1].y - a01);
            float c10 = a10 + wx * (P[c][2].y - a10);
            float c11 = a11 + wx * (P[c][3].y - a11);
            float c0 = c00 + wy * (c01 - c00);
            float c1 = c10 + wy * (c11 - c10);
            // streaming store: don't let output evict fr rows from L2
            __builtin_nontemporal_store(c0 + wz * (c1 - c0),
                                        &out[ob + ((size_t)c << 21)]);
        }
    }
}

extern "C" void kernel_launch(void* const* d_in, const int* in_sizes, int n_in,
                              void* d_out, int out_size, void* d_ws, size_t ws_size,
                              hipStream_t stream) {
    const float* fr       = (const float*)d_in[0];
    const float* seeds    = (const float*)d_in[1];
    const float* Pk       = (const float*)d_in[2];
    const float* defscale = (const float*)d_in[3];
    // d_in[4] = grid (values are exactly meshgrid(arange) -> recomputed in-kernel)
    const int*   feed_idx = (const int*)d_in[5];
    int fdim = in_sizes[2];

    float* S = (float*)d_ws;   // 8192 * 32 floats = 1 MB

    build_S<<<256, 256, 0, stream>>>(seeds, Pk, defscale, feed_idx, fdim, S);
    deform_sample<<<8192, 256, 0, stream>>>(fr, S, (float*)d_out);
}

// Round 3
// 266.528 us; speedup vs baseline: 1.0595x; 1.0595x over previous
//
#include <hip/hip_runtime.h>
#include <math.h>

// Problem constants
#define D0 32
#define D1 256
#define D2 256
#define HS2 129            // rfft half-spectrum last dim
#define NVOX (D0*D1*D2)    // 2097152
#define KMAX 4
#define NK 9               // k in [-4,4]
#define NK2 5              // k2 in [0,4]
#define NCH 3
#define BATCH 4
#define FCH 3
#define NBC (BATCH*FCH)    // 12
// C layout: [ch][i0][i1][i2][2]  (i0=k0+4, i1=k1+4, i2=k2)
#define C_FLOATS (NCH*NK*NK*NK2*2)   // 2430
// S layout: [zy][32] floats; slot = ch*10 + k2*2 + reim  (30 used, pad to 32)

typedef float v2f __attribute__((ext_vector_type(2)));

// ROUND 3 THEORY: dur has been pinned at 128us (<2% spread) across three
// structurally different SM-side kernels (instr count, MLP depth, wave count,
// reuse shape all varied -> null). The only invariants are the DRAM-visible
// ones: FETCH 71MB + WRITE 98MB at an effective 1.37 TB/s (21% of achievable).
// Suspect: the 98MB nontemporal-store stream bypasses L2/L3 write-combining
// and interleaves fine-grained DRAM writes with scattered row-segment reads
// -> constant bus turnaround -> read latency ~15K cy -> all waves vmcnt-idle
// (VALUBusy 27%, occupancy 81%, nothing SM-side saturated).
// Fix A: plain stores (L2 write-back coalesces output into sequential
//        full-line evictions; fr+out = 200MB fits the 256MB L3).
// Fix B: dense L3-warm pass over fr before the gather kernel, so deform's
//        reads hit L3 at stable latency instead of scattered cold HBM misses
//        inside the contended window.
// deform_sample is otherwise byte-identical to R1 for clean attribution.

// Dense grid-stride read of fr -> pulls all 100.7MB into L3 as a stream.
__global__ __launch_bounds__(256) void warm_l3(
    const float4* __restrict__ fr4, int n4)
{
    int tid = blockIdx.x * 256 + threadIdx.x;
    int stride = gridDim.x * 256;
    for (int i = tid; i < n4; i += stride) {
        float4 v = fr4[i];
        // keep the loads live, no dependent math chain
        asm volatile("" :: "v"(v.x), "v"(v.y), "v"(v.z), "v"(v.w));
    }
}

// 256 blocks x 256 threads: build dense C cube in LDS (scatter, ~fdim loads),
// then 32 zy rows/block, 81-mode sum split 8 ways across consecutive lanes,
// width-8 shuffle reduction.
__global__ __launch_bounds__(256) void build_S(
    const float* __restrict__ seeds, const float* __restrict__ Pk,
    const float* __restrict__ defscale, const int* __restrict__ feed_idx,
    int fdim, float* __restrict__ S)
{
    __shared__ float C[C_FLOATS];
    __shared__ int fed[NK*NK];
    int t = threadIdx.x;
    for (int i = t; i < C_FLOATS; i += 256) C[i] = 0.0f;
    if (t < NK*NK) fed[t] = 0;
    __syncthreads();
    float ds0 = defscale[0], ds1 = defscale[1], ds2 = defscale[2];
    const int STR_RI = D0 * D1 * HS2;   // 1056768
    const int STR_A  = D1 * HS2;        // 33024
    for (int j = t; j < fdim; j += 256) {
        int idx = feed_idx[j];
        int ri = idx / STR_RI; int r = idx - ri * STR_RI;
        int a  = r / STR_A;    r -= a * STR_A;
        int b  = r / HS2;      int c = r - b * HS2;
        int k0 = (a < D0/2) ? a : a - D0;
        int k1 = (b < D1/2) ? b : b - D1;
        if (k0 < -KMAX || k0 > KMAX || k1 < -KMAX || k1 > KMAX || c > KMAX) continue;
        int i0 = k0 + KMAX, i1 = k1 + KMAX;
        float pk = Pk[j];
        int base = ((i0*NK + i1)*NK2 + c)*2 + ri;
        C[base]                 = seeds[0*fdim + j] * pk * ds0;
        C[base + 1*NK*NK*NK2*2] = seeds[1*fdim + j] * pk * ds1;
        C[base + 2*NK*NK*NK2*2] = seeds[2*fdim + j] * pk * ds2;
        if (c == 0) fed[i0*NK + i1] = 1;
    }
    __syncthreads();
    // hermitian completion on the k2=0 plane: unfed <- conj(mirror)
    if (t < NK*NK && !fed[t]) {
        int i0 = t / NK, i1 = t - i0*NK;
        int m0 = (NK-1) - i0, m1 = (NK-1) - i1;
        for (int ch = 0; ch < NCH; ++ch) {
            int dst = ((ch*NK*NK + i0*NK + i1)*NK2 + 0)*2;
            int src = ((ch*NK*NK + m0*NK + m1)*NK2 + 0)*2;
            C[dst]   = C[src];
            C[dst+1] = -C[src+1];
        }
    }
    __syncthreads();

    int zyl = t >> 3;           // 0..31  (consecutive lanes share zyl)
    int g   = t & 7;            // mode group 0..7
    int zy = blockIdx.x * 32 + zyl;
    int z = zy >> 8, y = zy & 255;

    float w0r[NK], w0i[NK], w1r[NK], w1i[NK];
    {
        float th = (float)z * (6.28318530717958647692f / (float)D0);
        float sb, cb; __sincosf(th, &sb, &cb);
        w0r[KMAX] = 1.0f; w0i[KMAX] = 0.0f;
        float pr = 1.0f, pi = 0.0f;
        #pragma unroll
        for (int k = 1; k <= KMAX; ++k) {
            float nr = pr*cb - pi*sb, ni = pr*sb + pi*cb;
            pr = nr; pi = ni;
            w0r[KMAX+k] = pr; w0i[KMAX+k] = pi;
            w0r[KMAX-k] = pr; w0i[KMAX-k] = -pi;
        }
    }
    {
        float th = (float)y * (6.28318530717958647692f / (float)D1);
        float sb, cb; __sincosf(th, &sb, &cb);
        w1r[KMAX] = 1.0f; w1i[KMAX] = 0.0f;
        float pr = 1.0f, pi = 0.0f;
        #pragma unroll
        for (int k = 1; k <= KMAX; ++k) {
            float nr = pr*cb - pi*sb, ni = pr*sb + pi*cb;
            pr = nr; pi = ni;
            w1r[KMAX+k] = pr; w1i[KMAX+k] = pi;
            w1r[KMAX-k] = pr; w1i[KMAX-k] = -pi;
        }
    }

    float Sr[NCH*NK2], Si[NCH*NK2];
    #pragma unroll
    for (int i = 0; i < NCH*NK2; ++i) { Sr[i] = 0.0f; Si[i] = 0.0f; }

    for (int m = g; m < NK*NK; m += 8) {
        int i0 = m / NK, i1 = m - i0*NK;
        float Tr = w0r[i0]*w1r[i1] - w0i[i0]*w1i[i1];
        float Ti = w0r[i0]*w1i[i1] + w0i[i0]*w1r[i1];
        const float* Cp = C + m*NK2*2;
        #pragma unroll
        for (int ch = 0; ch < NCH; ++ch) {
            #pragma unroll
            for (int k2 = 0; k2 < NK2; ++k2) {
                float cr = Cp[ch*(NK*NK*NK2*2) + k2*2];
                float ci = Cp[ch*(NK*NK*NK2*2) + k2*2 + 1];
                int o = ch*NK2 + k2;
                Sr[o] += cr*Tr - ci*Ti;
                Si[o] += cr*Ti + ci*Tr;
            }
        }
    }

    #pragma unroll
    for (int off = 4; off >= 1; off >>= 1) {
        #pragma unroll
        for (int i = 0; i < NCH*NK2; ++i) {
            Sr[i] += __shfl_down(Sr[i], off, 8);
            Si[i] += __shfl_down(Si[i], off, 8);
        }
    }

    if (g == 0) {
        const float invN = 1.0f / (float)NVOX;
        float* Sp = S + (size_t)zy * 32;
        #pragma unroll
        for (int ch = 0; ch < NCH; ++ch) {
            #pragma unroll
            for (int k2 = 0; k2 < NK2; ++k2) {
                int o = ch*NK2 + k2;
                float sc = (k2 == 0) ? invN : 2.0f*invN;
                Sp[ch*10 + k2*2 + 0] = Sr[o] * sc;
                Sp[ch*10 + k2*2 + 1] = Si[o] * sc;
            }
        }
    }
}

__global__ __launch_bounds__(256) void deform_sample(
    const float* __restrict__ fr, const float* __restrict__ S,
    float* __restrict__ out)
{
    int i = blockIdx.x;                 // 32768 blocks
    int u = i & 7;                      // XCD id = unit id
    int b  = u >> 1;                    // batch (channel group) 0..3
    int zh = u & 1;                     // z-half 0..1
    int j = i >> 3;                     // 0..4095 within unit; y sweeps fastest
    int z = (zh << 4) + (j >> 8);
    int y = j & 255;
    int zy = (z << 8) + y;
    int x = threadIdx.x;

    // 30 wave-uniform coefficients -> scalar loads
    const float* __restrict__ Sp = S + (size_t)zy * 32;
    float s[30];
    #pragma unroll
    for (int q = 0; q < 30; ++q) s[q] = Sp[q];

    // cos/sin(k*theta) for k=1..4, theta = 2*pi*x/256
    float th = (float)x * (6.28318530717958647692f / (float)D2);
    float sb, cb; __sincosf(th, &sb, &cb);
    float ckr[KMAX], cks[KMAX];
    ckr[0] = cb; cks[0] = sb;
    #pragma unroll
    for (int k = 1; k < KMAX; ++k) {
        float nr = ckr[k-1]*cb - cks[k-1]*sb;
        float ni = cks[k-1]*cb + ckr[k-1]*sb;
        ckr[k] = nr; cks[k] = ni;
    }

    float d[NCH];
    #pragma unroll
    for (int ch = 0; ch < NCH; ++ch) {
        float acc = s[ch*10 + 0];
        #pragma unroll
        for (int k = 1; k <= KMAX; ++k)
            acc += s[ch*10 + k*2]*ckr[k-1] - s[ch*10 + k*2 + 1]*cks[k-1];
        d[ch] = acc;
    }

    // coordinates collapse to: f = clip(coord - disp, 0, dim-1)
    float fz = fminf(fmaxf((float)z - d[0], 0.0f), (float)(D0-1));
    float fy = fminf(fmaxf((float)y - d[1], 0.0f), (float)(D1-1));
    float fx = fminf(fmaxf((float)x - d[2], 0.0f), (float)(D2-1));

    float z0f = floorf(fz), y0f = floorf(fy), x0f = floorf(fx);
    int z0 = (int)z0f, y0 = (int)y0f, x0 = (int)x0f;
    int z1 = min(z0 + 1, D0-1), y1 = min(y0 + 1, D1-1);
    float wz = fz - z0f, wy = fy - y0f, wx = fx - x0f;

    int xm = min(x0, D2-2);             // float2 stays in-row
    bool hi = (x0 > xm);                // x0 == 255 -> use (.y,.y)

    int o00 = (z0 << 16) + (y0 << 8) + xm;
    int o01 = (z0 << 16) + (y1 << 8) + xm;
    int o10 = (z1 << 16) + (y0 << 8) + xm;
    int o11 = (z1 << 16) + (y1 << 8) + xm;

    // issue all 12 float2 gathers before consuming (MLP)
    v2f P[FCH][4];
    #pragma unroll
    for (int c = 0; c < FCH; ++c) {
        const float* __restrict__ v = fr + ((size_t)(b*FCH + c) << 21);
        P[c][0] = *(const v2f*)(v + o00);
        P[c][1] = *(const v2f*)(v + o01);
        P[c][2] = *(const v2f*)(v + o10);
        P[c][3] = *(const v2f*)(v + o11);
    }
    asm volatile("" :
        "+v"(P[0][0]), "+v"(P[0][1]), "+v"(P[0][2]), "+v"(P[0][3]),
        "+v"(P[1][0]), "+v"(P[1][1]), "+v"(P[1][2]), "+v"(P[1][3]),
        "+v"(P[2][0]), "+v"(P[2][1]), "+v"(P[2][2]), "+v"(P[2][3]));
    __builtin_amdgcn_sched_barrier(0);

    size_t ob = ((size_t)(b*FCH) << 21) + ((size_t)zy << 8) + x;
    #pragma unroll
    for (int c = 0; c < FCH; ++c) {
        float a00 = hi ? P[c][0].y : P[c][0].x;
        float a01 = hi ? P[c][1].y : P[c][1].x;
        float a10 = hi ? P[c][2].y : P[c][2].x;
        float a11 = hi ? P[c][3].y : P[c][3].x;
        float c00 = a00 + wx * (P[c][0].y - a00);
        float c01 = a01 + wx * (P[c][1].y - a01);
        float c10 = a10 + wx * (P[c][2].y - a10);
        float c11 = a11 + wx * (P[c][3].y - a11);
        float c0 = c00 + wy * (c01 - c00);
        float c1 = c10 + wy * (c11 - c10);
        // ROUND 3: plain store (was nontemporal). Let L2 write-back batch the
        // output into full-line sequential evictions instead of fine-grained
        // nt writes interleaving with reads at the DRAM bus.
        out[ob + ((size_t)c << 21)] = c0 + wz * (c1 - c0);
    }
}

extern "C" void kernel_launch(void* const* d_in, const int* in_sizes, int n_in,
                              void* d_out, int out_size, void* d_ws, size_t ws_size,
                              hipStream_t stream) {
    const float* fr       = (const float*)d_in[0];
    const float* seeds    = (const float*)d_in[1];
    const float* Pk       = (const float*)d_in[2];
    const float* defscale = (const float*)d_in[3];
    // d_in[4] = grid (values are exactly meshgrid(arange) -> recomputed in-kernel)
    const int*   feed_idx = (const int*)d_in[5];
    int fdim = in_sizes[2];

    float* S = (float*)d_ws;   // 8192 * 32 floats = 1 MB

    // Warm L3 with a dense sequential read of fr (100.7 MB), so the gather
    // kernel's scattered reads hit L3 instead of cold HBM.
    int n4 = (BATCH * FCH * NVOX) / 4;   // float4 count = 6291456
    warm_l3<<<2048, 256, 0, stream>>>((const float4*)fr, n4);
    build_S<<<256, 256, 0, stream>>>(seeds, Pk, defscale, feed_idx, fdim, S);
    deform_sample<<<32768, 256, 0, stream>>>(fr, S, (float*)d_out);
}